// Round 1
// baseline (1010.912 us; speedup 1.0000x reference)
//
#include <hip/hip_runtime.h>
#include <math.h>

// Problem constants (fixed by reference)
#define NS 128       // scalar channels
#define TD 480       // total dim per row
#define NF 224       // gate channels (128 scalar + 96 vector)
#define BN 112       // bottleneck dim
#define TM 64        // rows per block
#define K1 224       // GEMM1 K
#define K1S 232      // gate_A / W1T LDS stride (bf16 elems; 464B = 16B-aligned, bank-friendly)
#define K2S 136      // h_A / W2T LDS stride (K padded 112->128, +8 pad; 272B)
#define GS 225       // gates f32 stride (breaks 4-quad bank collision)
#define W1T_ELEMS (BN * K1S)   // 25984 bf16
#define W2T_ELEMS (NF * K2S)   // 30464 bf16

typedef __bf16 bf16x8 __attribute__((ext_vector_type(8)));
typedef float f32x4 __attribute__((ext_vector_type(4)));

__device__ __forceinline__ unsigned short f2bf(float f) {
  union { float f; unsigned u; } v; v.f = f;
  unsigned r = v.u + 0x7FFFu + ((v.u >> 16) & 1u);   // RTNE
  return (unsigned short)(r >> 16);
}

struct __align__(16) SMem {
  unsigned short gateA[TM * K1S];  // 29696 B  (A operand, GEMM1)
  unsigned short hA[TM * K2S];     // 17408 B  (A operand, GEMM2; k in [112,128) zeroed)
  unsigned short W[W2T_ELEMS];     // 60928 B  (holds W1T then W2T)
  float rowbuf[4][352];            // 5632 B   (per-wave squared vector entries)
  float b1s[BN];
  float b2s[NF];
  float aws[NF];                   // affine_weight
  float absb[NS];                  // affine_bias
  float meanv[TM];
};
// gates f32 tile (TM x GS = 57600 B) aliases gateA|hA|W (108032 B) after GEMM2.

__global__ void prep_kernel(const float* __restrict__ W1, const float* __restrict__ W2,
                            unsigned short* __restrict__ w1t, unsigned short* __restrict__ w2t) {
  int t = blockIdx.x * 256 + threadIdx.x;
  if (t < W1T_ELEMS) {
    int n = t / K1S, k = t - n * K1S;
    float v = (k < K1) ? W1[k * BN + n] : 0.0f;   // W1 is (224,112) row-major -> W1T[n][k]
    w1t[t] = f2bf(v);
  } else {
    int t2 = t - W1T_ELEMS;
    if (t2 < W2T_ELEMS) {
      int n = t2 / K2S, k = t2 - n * K2S;
      float v = (k < BN) ? W2[k * NF + n] : 0.0f; // W2 is (112,224) -> W2T[n][k], k-pad zeroed
      w2t[t2] = f2bf(v);
    }
  }
}

__global__ __launch_bounds__(256, 1) void fused_kernel(
    const float* __restrict__ X,
    const float* __restrict__ b1, const float* __restrict__ b2,
    const float* __restrict__ aw, const float* __restrict__ ab,
    const unsigned short* __restrict__ w1t, const unsigned short* __restrict__ w2t,
    float* __restrict__ OUT) {
  __shared__ SMem sm;
  const int tid  = threadIdx.x;
  const int lane = tid & 63;
  const int w    = tid >> 6;
  const int l15  = lane & 15;
  const int quad = lane >> 4;
  const int R0   = blockIdx.x * TM;

  // ---- stage small params into LDS ----
  for (int t = tid; t < 688; t += 256) {
    if (t < 112)      sm.b1s[t]        = b1[t];
    else if (t < 336) sm.b2s[t - 112]  = b2[t - 112];
    else if (t < 560) sm.aws[t - 336]  = aw[t - 336];
    else              sm.absb[t - 560] = ab[t - 560];
  }
  // ---- zero hA K-pad [112,128) ----
  for (int t = tid; t < 512; t += 256) {
    int r = t >> 3, j = t & 7;
    *(unsigned int*)&sm.hA[r * K2S + 112 + 2 * j] = 0u;
  }
  // ---- copy W1T (bf16, pre-transposed) into LDS ----
  {
    const float4* src = (const float4*)w1t;
    float4* dst = (float4*)sm.W;
    #pragma unroll
    for (int it = 0; it < 13; ++it) {
      int t = tid + it * 256;
      if (t < (W1T_ELEMS / 8)) dst[t] = src[t];
    }
  }

  // ---- phase 1: per-row stats + gate_in (wave w owns rows [16w,16w+16)) ----
  {
    float cur[8], nxt[8];
    const int rbase = 16 * w;
    auto loadRow = [&](int rl, float* v) {
      const float* rp = X + (size_t)(R0 + rl) * TD + lane;
      #pragma unroll
      for (int k = 0; k < 7; ++k) v[k] = rp[64 * k];
      v[7] = (lane < 32) ? rp[448] : 0.0f;
    };
    auto procRow = [&](int rl, float* v) {
      float ssum = v[0] + v[1];                       // cols lane, lane+64 -> all 128 scalars
      #pragma unroll
      for (int m = 32; m >= 1; m >>= 1) ssum += __shfl_xor(ssum, m, 64);
      float mean = ssum * (1.0f / 128.0f);
      float* rb = sm.rowbuf[w];
      rb[lane]       = v[2] * v[2];
      rb[lane + 64]  = v[3] * v[3];
      rb[lane + 128] = v[4] * v[4];
      rb[lane + 192] = v[5] * v[5];
      rb[lane + 256] = v[6] * v[6];
      if (lane < 32) rb[lane + 320] = v[7] * v[7];
      __builtin_amdgcn_wave_barrier();                // same-wave DS in-order; block reordering
      float s3 = rb[3 * lane] + rb[3 * lane + 1] + rb[3 * lane + 2];
      float r3 = sqrtf(s3 * (1.0f / 3.0f) + 1e-6f);
      unsigned short* ga = &sm.gateA[rl * K1S];
      ga[lane]       = f2bf(v[0] - mean);
      ga[lane + 64]  = f2bf(v[1] - mean);
      ga[lane + 128] = f2bf(r3);
      if (lane < 32) {
        float s5 = 0.0f;
        #pragma unroll
        for (int q = 0; q < 5; ++q) s5 += rb[192 + 5 * lane + q];
        ga[lane + 192] = f2bf(sqrtf(s5 * 0.2f + 1e-6f));
      }
      if (lane == 0) sm.meanv[rl] = mean;
      __builtin_amdgcn_wave_barrier();
    };
    loadRow(rbase, cur);
    #pragma unroll
    for (int i = 0; i < 16; ++i) {                    // SW pipeline: prefetch row i+1
      if (i < 15) loadRow(rbase + i + 1, nxt);
      procRow(rbase + i, cur);
      #pragma unroll
      for (int k = 0; k < 8; ++k) cur[k] = nxt[k];
    }
  }
  __syncthreads();

  // ---- GEMM1: h = silu(gate_in @ W1 + b1), 16x16x32 bf16 MFMA, K=224 ----
  {
    f32x4 acc[7];
    #pragma unroll
    for (int j = 0; j < 7; ++j) acc[j] = (f32x4){0.f, 0.f, 0.f, 0.f};
    const unsigned short* gA = &sm.gateA[(16 * w + l15) * K1S];
    #pragma unroll
    for (int kk = 0; kk < 7; ++kk) {
      bf16x8 a = *(const bf16x8*)(gA + kk * 32 + quad * 8);
      #pragma unroll
      for (int nb = 0; nb < 7; ++nb) {
        bf16x8 bb = *(const bf16x8*)(&sm.W[(nb * 16 + l15) * K1S + kk * 32 + quad * 8]);
        acc[nb] = __builtin_amdgcn_mfma_f32_16x16x32_bf16(a, bb, acc[nb], 0, 0, 0);
      }
    }
    #pragma unroll
    for (int nb = 0; nb < 7; ++nb) {
      int n = nb * 16 + l15;
      float bias = sm.b1s[n];
      #pragma unroll
      for (int i = 0; i < 4; ++i) {
        int r = 16 * w + quad * 4 + i;                // C layout: col=lane&15, row=quad*4+i
        float hv = acc[nb][i] + bias;
        float sg = 1.0f / (1.0f + __expf(-hv));
        sm.hA[r * K2S + n] = f2bf(hv * sg);
      }
    }
  }
  __syncthreads();

  // ---- swap in W2T ----
  {
    const float4* src = (const float4*)w2t;
    float4* dst = (float4*)sm.W;
    #pragma unroll
    for (int it = 0; it < 15; ++it) {
      int t = tid + it * 256;
      if (t < (W2T_ELEMS / 8)) dst[t] = src[t];
    }
  }
  __syncthreads();

  // ---- GEMM2: gates = 2*sigmoid(h @ W2 + b2) * affine_weight, K=128 (padded) ----
  float garr[56];
  {
    f32x4 acc[14];
    #pragma unroll
    for (int j = 0; j < 14; ++j) acc[j] = (f32x4){0.f, 0.f, 0.f, 0.f};
    const unsigned short* hA = &sm.hA[(16 * w + l15) * K2S];
    #pragma unroll
    for (int kk = 0; kk < 4; ++kk) {
      bf16x8 a = *(const bf16x8*)(hA + kk * 32 + quad * 8);
      #pragma unroll
      for (int nb = 0; nb < 14; ++nb) {
        bf16x8 bb = *(const bf16x8*)(&sm.W[(nb * 16 + l15) * K2S + kk * 32 + quad * 8]);
        acc[nb] = __builtin_amdgcn_mfma_f32_16x16x32_bf16(a, bb, acc[nb], 0, 0, 0);
      }
    }
    #pragma unroll
    for (int nb = 0; nb < 14; ++nb) {
      int n = nb * 16 + l15;
      float b2v = sm.b2s[n], awv = sm.aws[n];
      #pragma unroll
      for (int i = 0; i < 4; ++i) {
        float z = acc[nb][i] + b2v;
        garr[nb * 4 + i] = 2.0f * awv / (1.0f + __expf(-z));
      }
    }
  }
  __syncthreads();                                    // all waves done reading hA/W2T
  float* gates = (float*)&sm;                         // alias over gateA|hA|W
  #pragma unroll
  for (int nb = 0; nb < 14; ++nb) {
    #pragma unroll
    for (int i = 0; i < 4; ++i) {
      int r = 16 * w + quad * 4 + i;
      gates[r * GS + nb * 16 + l15] = garr[nb * 4 + i];
    }
  }
  __syncthreads();

  // ---- phase 3: coalesced re-read of x (L2-warm), scale, store ----
  const float* Xb = X + (size_t)R0 * TD;
  float* Ob = OUT + (size_t)R0 * TD;
  #pragma unroll 3
  for (int it = 0; it < 30; ++it) {                   // 64*480/4 / 256 = 30 exactly
    int u = tid + it * 256;
    int e = u * 4;
    int r = e / TD;
    int c = e - r * TD;                               // float4 never crosses a row (480%4==0)
    float4 xv = *(const float4*)(Xb + e);
    float m = sm.meanv[r];
    float xin[4] = {xv.x, xv.y, xv.z, xv.w};
    float out[4];
    #pragma unroll
    for (int i = 0; i < 4; ++i) {
      int ci = c + i;
      int ch = (ci < NS) ? ci
             : ((ci < 320) ? (NS + (ci - NS) / 3) : (192 + (ci - 320) / 5));
      float g = gates[r * GS + ch];
      out[i] = (ci < NS) ? ((xin[i] - m) * g + sm.absb[ci]) : (xin[i] * g);
    }
    float4 ov = {out[0], out[1], out[2], out[3]};
    *(float4*)(Ob + e) = ov;
  }
}

extern "C" void kernel_launch(void* const* d_in, const int* in_sizes, int n_in,
                              void* d_out, int out_size, void* d_ws, size_t ws_size,
                              hipStream_t stream) {
  const float* X  = (const float*)d_in[0];
  const float* W1 = (const float*)d_in[1];
  const float* b1 = (const float*)d_in[2];
  const float* W2 = (const float*)d_in[3];
  const float* b2 = (const float*)d_in[4];
  const float* aw = (const float*)d_in[5];
  const float* ab = (const float*)d_in[6];
  float* OUT = (float*)d_out;
  unsigned short* w1t = (unsigned short*)d_ws;
  unsigned short* w2t = w1t + W1T_ELEMS;              // ~113 KB of d_ws total

  int n = in_sizes[0] / TD;                           // 200000 (divisible by TM=64)
  int pb = (W1T_ELEMS + W2T_ELEMS + 255) / 256;
  hipLaunchKernelGGL(prep_kernel, dim3(pb), dim3(256), 0, stream, W1, W2, w1t, w2t);
  hipLaunchKernelGGL(fused_kernel, dim3(n / TM), dim3(256), 0, stream,
                     X, b1, b2, aw, ab, w1t, w2t, OUT);
}